// Round 6
// baseline (242.827 us; speedup 1.0000x reference)
//
#include <hip/hip_runtime.h>
#include <hip/hip_bf16.h>

// GAT layer for MI355X (gfx950). FP32 in/out.
//   K1 gat_wh   : Wh = h @ W^T via split-bf16 MFMA -> WhT_hi/lo[128][8192] bf16.
//   K2 gat_f12  : f1/f2 logits (fp32, pre-scaled by log2e).
//   K3 gat_flash: barrier-free per-wave flash softmax+PV.
//     R4/R5 post-mortem: register-copy rotation at the loop tail forced a
//     vmcnt(0)-equivalent drain every step (copies need the newest load) and
//     let the compiler sink the prefetches (VGPR 44/104) -> one serialized
//     memory latency per step, 0.66 TB/s. This version uses STATIC PARITY
//     BUFFERS refilled in place (no copies ever): adj in 4 bufs (distance 4),
//     B/f2 in 2 bufs (distance 2), adj issued LAST each step so counted
//     B-waits never retire young adj. sched_barrier(0) per step stops sinking.

typedef __bf16 bf16;
typedef __attribute__((ext_vector_type(8))) __bf16 bf16x8;
typedef __attribute__((ext_vector_type(4))) float f32x4;

#define NN 8192
#define F_IN 256
#define F_OUT 128
#define LOG2E 1.44269504088896f
#define ALPHA 0.2f

__device__ __forceinline__ void split8(const float* __restrict__ p,
                                       bf16x8& hi, bf16x8& lo) {
    const float4 u = *(const float4*)p;
    const float4 v = *(const float4*)(p + 4);
    float f[8] = {u.x, u.y, u.z, u.w, v.x, v.y, v.z, v.w};
#pragma unroll
    for (int j = 0; j < 8; ++j) {
        const bf16 h = (bf16)f[j];
        hi[j] = h;
        lo[j] = (bf16)(f[j] - (float)h);
    }
}

// ---------------------------------------------------------------------------
// K1: Wh = h @ W^T (8192x128, K=256) -> transposed bf16 planes. (~3 us)
// ---------------------------------------------------------------------------
__global__ __launch_bounds__(128) void gat_wh(const float* __restrict__ h,
                                              const float* __restrict__ W,
                                              bf16* __restrict__ WhT_hi,
                                              bf16* __restrict__ WhT_lo) {
    const int tid = threadIdx.x;
    const int wv = tid >> 6;
    const int l15 = tid & 15;
    const int g = (tid & 63) >> 4;
    const int rowbase = blockIdx.x * 32 + wv * 16;

    f32x4 acc[8];
    const f32x4 zz = {0.f, 0.f, 0.f, 0.f};
#pragma unroll
    for (int nf = 0; nf < 8; ++nf) acc[nf] = zz;

#pragma unroll
    for (int ks = 0; ks < 8; ++ks) {
        const int k = ks * 32 + g * 8;
        bf16x8 ah, al;
        split8(h + (size_t)(rowbase + l15) * F_IN + k, ah, al);
#pragma unroll
        for (int nf = 0; nf < 8; ++nf) {
            bf16x8 bh, bl;
            split8(W + (size_t)(nf * 16 + l15) * F_IN + k, bh, bl);
            acc[nf] = __builtin_amdgcn_mfma_f32_16x16x32_bf16(ah, bh, acc[nf], 0, 0, 0);
            acc[nf] = __builtin_amdgcn_mfma_f32_16x16x32_bf16(ah, bl, acc[nf], 0, 0, 0);
            acc[nf] = __builtin_amdgcn_mfma_f32_16x16x32_bf16(al, bh, acc[nf], 0, 0, 0);
        }
    }

#pragma unroll
    for (int nf = 0; nf < 8; ++nf)
#pragma unroll
        for (int r = 0; r < 4; ++r) {
            const int row = rowbase + g * 4 + r;
            const int c = nf * 16 + l15;
            const float val = acc[nf][r];
            const bf16 vh = (bf16)val;
            WhT_hi[(size_t)c * NN + row] = vh;
            WhT_lo[(size_t)c * NN + row] = (bf16)(val - (float)vh);
        }
}

// ---------------------------------------------------------------------------
// K2: f1/f2 (fp32, pre-scaled by log2e). (~1 us)
// ---------------------------------------------------------------------------
__global__ __launch_bounds__(64) void gat_f12(const bf16* __restrict__ WhT_hi,
                                              const bf16* __restrict__ WhT_lo,
                                              const float* __restrict__ a,
                                              float* __restrict__ f1L,
                                              float* __restrict__ f2L) {
    const int i = blockIdx.x * 64 + threadIdx.x;
    float s1 = 0.f, s2 = 0.f;
#pragma unroll 8
    for (int c = 0; c < F_OUT; ++c) {
        const float wh = (float)WhT_hi[(size_t)c * NN + i] +
                         (float)WhT_lo[(size_t)c * NN + i];
        s1 += wh * a[c];
        s2 += wh * a[F_OUT + c];
    }
    f1L[i] = s1 * LOG2E;
    f2L[i] = s2 * LOG2E;
}

// ---------------------------------------------------------------------------
// K3: 256 blocks x 512 thr (8 waves = colh(2) x kq(4)), no main-loop barriers.
// Wave: rows [r0,r0+32), cols [64*colh,+64), k-slice 2048 (64 steps of 32).
// STEP(t): compute P(t) in A-frag layout -> 16 MFMAs; refill B/f2 <- t+2,
// adj <- t+4 (issued LAST); sched_barrier(0). All buffers are named statics
// refilled in place -> compiler emits counted vmcnt waits, queue never drains.
// ---------------------------------------------------------------------------
#define STEP(T, XA0, XA1, XB0, XB1, BH, BL, FA, FB)                              \
    do {                                                                         \
        const int aa_[8] = {XA0.x, XA0.y, XA0.z, XA0.w, XA1.x, XA1.y, XA1.z, XA1.w}; \
        const int ab_[8] = {XB0.x, XB0.y, XB0.z, XB0.w, XB1.x, XB1.y, XB1.z, XB1.w}; \
        const float ff_[8] = {FA.x, FA.y, FA.z, FA.w, FB.x, FB.y, FB.z, FB.w};   \
        bf16x8 pa_, pb_;                                                         \
        _Pragma("unroll") for (int j = 0; j < 8; ++j) {                          \
            const float xa_ = f1a + ff_[j];                                      \
            const float xb_ = f1b + ff_[j];                                      \
            const float ea_ = __builtin_amdgcn_exp2f(fmaxf(xa_, ALPHA * xa_));   \
            const float eb_ = __builtin_amdgcn_exp2f(fmaxf(xb_, ALPHA * xb_));   \
            pa_[j] = (bf16)(aa_[j] > 0 ? ea_ : 0.f);                             \
            pb_[j] = (bf16)(ab_[j] > 0 ? eb_ : 0.f);                             \
        }                                                                        \
        _Pragma("unroll") for (int j = 0; j < 8; ++j) {                          \
            rsa += (float)pa_[j];                                                \
            rsb += (float)pb_[j];                                                \
        }                                                                        \
        _Pragma("unroll") for (int ct = 0; ct < 4; ++ct) {                       \
            accA[ct] = __builtin_amdgcn_mfma_f32_16x16x32_bf16(pa_, BH[ct], accA[ct], 0, 0, 0); \
            accA[ct] = __builtin_amdgcn_mfma_f32_16x16x32_bf16(pa_, BL[ct], accA[ct], 0, 0, 0); \
            accB[ct] = __builtin_amdgcn_mfma_f32_16x16x32_bf16(pb_, BH[ct], accB[ct], 0, 0, 0); \
            accB[ct] = __builtin_amdgcn_mfma_f32_16x16x32_bf16(pb_, BL[ct], accB[ct], 0, 0, 0); \
        }                                                                        \
        {                                                                        \
            const int k2_ = ((T) + 2 < 64 ? (T) + 2 : 63) * 32;                  \
            const int k4_ = ((T) + 4 < 64 ? (T) + 4 : 63) * 32;                  \
            _Pragma("unroll") for (int ct = 0; ct < 4; ++ct) {                   \
                BH[ct] = *(const bf16x8*)(bhp + (size_t)ct * 16 * NN + k2_);     \
                BL[ct] = *(const bf16x8*)(blp + (size_t)ct * 16 * NN + k2_);     \
            }                                                                    \
            FA = *(const float4*)(f2p + k2_);                                    \
            FB = *(const float4*)(f2p + k2_ + 4);                                \
            XA0 = *(const int4*)(arA + k4_);                                     \
            XA1 = *(const int4*)(arA + k4_ + 4);                                 \
            XB0 = *(const int4*)(arB + k4_);                                     \
            XB1 = *(const int4*)(arB + k4_ + 4);                                 \
        }                                                                        \
        __builtin_amdgcn_sched_barrier(0);                                       \
    } while (0)

__global__ __launch_bounds__(512, 2) void gat_flash(const int* __restrict__ adj,
                                                    const bf16* __restrict__ WhT_hi,
                                                    const bf16* __restrict__ WhT_lo,
                                                    const float* __restrict__ f1L,
                                                    const float* __restrict__ f2L,
                                                    float* __restrict__ out) {
    __shared__ float accL[32][128];
    __shared__ float rsL[32];

    const int tid = threadIdx.x;
    const int wv = tid >> 6;   // 0..7
    const int kq = wv >> 1;    // 0..3 : k-slice of 2048
    const int colh = wv & 1;   // 0..1 : col half of 64
    const int l = tid & 63;
    const int l15 = l & 15;
    const int g = l >> 4;
    const int r0 = blockIdx.x * 32;

    const int kbase = kq * 2048;
    const float f1a = f1L[r0 + l15];
    const float f1b = f1L[r0 + 16 + l15];

    const int* arA = adj + (size_t)(r0 + l15) * NN + kbase + g * 8;
    const int* arB = arA + (size_t)16 * NN;
    const float* f2p = f2L + kbase + g * 8;
    const bf16* bhp = WhT_hi + (size_t)(colh * 64 + l15) * NN + kbase + g * 8;
    const bf16* blp = WhT_lo + (size_t)(colh * 64 + l15) * NN + kbase + g * 8;

    f32x4 accA[4], accB[4];
    const f32x4 zz = {0.f, 0.f, 0.f, 0.f};
#pragma unroll
    for (int ct = 0; ct < 4; ++ct) { accA[ct] = zz; accB[ct] = zz; }
    float rsa = 0.f, rsb = 0.f;

    // ---- prologue: B/f2 for steps 0,1 first; adj for steps 0..3 LAST ----
    bf16x8 BH0[4], BL0[4], BH1[4], BL1[4];
#pragma unroll
    for (int ct = 0; ct < 4; ++ct) {
        BH0[ct] = *(const bf16x8*)(bhp + (size_t)ct * 16 * NN);
        BL0[ct] = *(const bf16x8*)(blp + (size_t)ct * 16 * NN);
    }
    float4 f2a0 = *(const float4*)(f2p);
    float4 f2b0 = *(const float4*)(f2p + 4);
#pragma unroll
    for (int ct = 0; ct < 4; ++ct) {
        BH1[ct] = *(const bf16x8*)(bhp + (size_t)ct * 16 * NN + 32);
        BL1[ct] = *(const bf16x8*)(blp + (size_t)ct * 16 * NN + 32);
    }
    float4 f2a1 = *(const float4*)(f2p + 32);
    float4 f2b1 = *(const float4*)(f2p + 36);

    int4 x0a0 = *(const int4*)(arA);
    int4 x0a1 = *(const int4*)(arA + 4);
    int4 x0b0 = *(const int4*)(arB);
    int4 x0b1 = *(const int4*)(arB + 4);
    int4 x1a0 = *(const int4*)(arA + 32);
    int4 x1a1 = *(const int4*)(arA + 36);
    int4 x1b0 = *(const int4*)(arB + 32);
    int4 x1b1 = *(const int4*)(arB + 36);
    int4 x2a0 = *(const int4*)(arA + 64);
    int4 x2a1 = *(const int4*)(arA + 68);
    int4 x2b0 = *(const int4*)(arB + 64);
    int4 x2b1 = *(const int4*)(arB + 68);
    int4 x3a0 = *(const int4*)(arA + 96);
    int4 x3a1 = *(const int4*)(arA + 100);
    int4 x3b0 = *(const int4*)(arB + 96);
    int4 x3b1 = *(const int4*)(arB + 100);
    __builtin_amdgcn_sched_barrier(0);

    for (int u = 0; u < 16; ++u) {
        const int t = u * 4;
        STEP(t + 0, x0a0, x0a1, x0b0, x0b1, BH0, BL0, f2a0, f2b0);
        STEP(t + 1, x1a0, x1a1, x1b0, x1b1, BH1, BL1, f2a1, f2b1);
        STEP(t + 2, x2a0, x2a1, x2b0, x2b1, BH0, BL0, f2a0, f2b0);
        STEP(t + 3, x3a0, x3a1, x3b0, x3b1, BH1, BL1, f2a1, f2b1);
    }

    // rowsum: combine the 4 g-groups (lanes with equal l15)
    rsa += __shfl_xor(rsa, 16);
    rsa += __shfl_xor(rsa, 32);
    rsb += __shfl_xor(rsb, 16);
    rsb += __shfl_xor(rsb, 32);

    // phased k-split reduction over kq. D layout: row=4*(l>>4)+reg, col=l&15.
    for (int ph = 0; ph < 4; ++ph) {
        if (kq == ph) {
            const int colb = colh * 64 + l15;
#pragma unroll
            for (int ct = 0; ct < 4; ++ct)
#pragma unroll
                for (int r = 0; r < 4; ++r) {
                    const int col = colb + ct * 16;
                    const int rowA = g * 4 + r;
                    const int rowB = 16 + g * 4 + r;
                    if (ph == 0) {
                        accL[rowA][col] = accA[ct][r];
                        accL[rowB][col] = accB[ct][r];
                    } else {
                        accL[rowA][col] += accA[ct][r];
                        accL[rowB][col] += accB[ct][r];
                    }
                }
            if (colh == 0 && l < 16) {
                if (ph == 0) {
                    rsL[l15] = rsa;
                    rsL[16 + l15] = rsb;
                } else {
                    rsL[l15] += rsa;
                    rsL[16 + l15] += rsb;
                }
            }
        }
        __syncthreads();
    }

    // divide + store: 512 thr x 8 floats = 32x128 tile
    const int row = tid >> 4;
    const int col = (tid & 15) * 8;
    const float inv = 1.0f / rsL[row];
    float4 v0 = *(const float4*)&accL[row][col];
    float4 v1 = *(const float4*)&accL[row][col + 4];
    v0.x *= inv; v0.y *= inv; v0.z *= inv; v0.w *= inv;
    v1.x *= inv; v1.y *= inv; v1.z *= inv; v1.w *= inv;
    *(float4*)(out + (size_t)(r0 + row) * F_OUT + col) = v0;
    *(float4*)(out + (size_t)(r0 + row) * F_OUT + col + 4) = v1;
}

// ---------------------------------------------------------------------------
extern "C" void kernel_launch(void* const* d_in, const int* in_sizes, int n_in,
                              void* d_out, int out_size, void* d_ws, size_t ws_size,
                              hipStream_t stream) {
    const float* h = (const float*)d_in[0];  // (8192, 256) fp32
    const int* adj = (const int*)d_in[1];    // (8192, 8192) int32
    const float* W = (const float*)d_in[2];  // (128, 256) fp32
    const float* a = (const float*)d_in[3];  // (1, 256) fp32
    float* out = (float*)d_out;              // (8192, 128) fp32

    char* ws = (char*)d_ws;
    bf16* WhT_hi = (bf16*)ws;                              // 2 MB
    bf16* WhT_lo = (bf16*)(ws + (size_t)2 * 1024 * 1024);  // 2 MB
    float* f1L = (float*)(ws + (size_t)4 * 1024 * 1024);   // 32 KB
    float* f2L = f1L + NN;                                 // 32 KB

    gat_wh<<<256, 128, 0, stream>>>(h, W, WhT_hi, WhT_lo);
    gat_f12<<<NN / 64, 64, 0, stream>>>(WhT_hi, WhT_lo, a, f1L, f2L);
    gat_flash<<<NN / 32, 512, 0, stream>>>(adj, WhT_hi, WhT_lo, f1L, f2L, out);
}